// Round 1
// baseline (188.451 us; speedup 1.0000x reference)
//
#include <hip/hip_runtime.h>
#include <cstdint>

#define ALPHA_LR 0.2f

static constexpr int Bc = 32, Tc = 128, Fc = 32, Hc = 4, HDc = 16, RKc = 16;
static constexpr int Nc = Tc * Fc;  // 4096

__device__ __forceinline__ uint32_t rotl32(uint32_t v, int r) {
  return (v << r) | (v >> (32 - r));
}

// Threefry-2x32, 20 rounds (JAX's PRNG cipher). (x0,x1) encrypted with key (k0,k1).
__device__ __forceinline__ void threefry2x32(uint32_t k0, uint32_t k1,
                                             uint32_t& x0, uint32_t& x1) {
  uint32_t k2 = k0 ^ k1 ^ 0x1BD11BDAu;
  x0 += k0; x1 += k1;
#define TF_R(r) { x0 += x1; x1 = rotl32(x1, (r)); x1 ^= x0; }
  TF_R(13) TF_R(15) TF_R(26) TF_R(6)
  x0 += k1; x1 += k2 + 1u;
  TF_R(17) TF_R(29) TF_R(16) TF_R(24)
  x0 += k2; x1 += k0 + 2u;
  TF_R(13) TF_R(15) TF_R(26) TF_R(6)
  x0 += k0; x1 += k1 + 3u;
  TF_R(17) TF_R(29) TF_R(16) TF_R(24)
  x0 += k1; x1 += k2 + 4u;
  TF_R(13) TF_R(15) TF_R(26) TF_R(6)
  x0 += k2; x1 += k0 + 5u;
#undef TF_R
}

// XLA ErfInv32 (Giles 2012) — matches lax.erf_inv on f32.
__device__ __forceinline__ float erfinv_f32(float x) {
  float w = -logf((1.0f - x) * (1.0f + x));
  float p;
  if (w < 5.0f) {
    w -= 2.5f;
    p = 2.81022636e-08f;
    p = fmaf(p, w, 3.43273939e-07f);
    p = fmaf(p, w, -3.5233877e-06f);
    p = fmaf(p, w, -4.39150654e-06f);
    p = fmaf(p, w, 0.00021858087f);
    p = fmaf(p, w, -0.00125372503f);
    p = fmaf(p, w, -0.00417768164f);
    p = fmaf(p, w, 0.246640727f);
    p = fmaf(p, w, 1.50140941f);
  } else {
    w = sqrtf(w) - 3.0f;
    p = -0.000200214257f;
    p = fmaf(p, w, 0.000100950558f);
    p = fmaf(p, w, 0.00134934322f);
    p = fmaf(p, w, -0.00367342844f);
    p = fmaf(p, w, 0.00573950773f);
    p = fmaf(p, w, -0.0076224613f);
    p = fmaf(p, w, 0.00943887047f);
    p = fmaf(p, w, 1.00167406f);
    p = fmaf(p, w, 2.83297682f);
  }
  return p * x;
}

// jax.random.normal f32 path: bits -> uniform in [lo,1) -> sqrt(2)*erfinv
__device__ __forceinline__ float jax_normal_from_bits(uint32_t bits) {
  const float lo = -0.99999994f;  // nextafter(-1,0)
  float f = __uint_as_float((bits >> 9) | 0x3f800000u) - 1.0f;  // [0,1)
  float u = fmaxf(lo, f * 2.0f + lo);  // (hi-lo) rounds to 2.0f in f32
  return 1.41421354f * erfinv_f32(u);
}

// ---------------------------------------------------------------------------
// Stage A: one block per head. Computes fa, ta (+transpose), rowsums, s,
// v0 (threefry), 3-step power iteration, sn.
// ---------------------------------------------------------------------------
__global__ __launch_bounds__(1024)
void stageA_kernel(const float* __restrict__ x, const float* __restrict__ weight,
                   const float* __restrict__ tqg, const float* __restrict__ tkg,
                   const float* __restrict__ ffg,
                   float* __restrict__ ws_ta, float* __restrict__ ws_taT,
                   float* __restrict__ ws_fa, float* __restrict__ ws_s,
                   float* __restrict__ ws_sn) {
  const int h = blockIdx.x;
  const int tid = (int)threadIdx.x;
  const int lane = tid & 63;
  const int wv = tid >> 6;

  __shared__ float bufA[Nc];        // q[B][T]  -> later v
  __shared__ float bufB[Nc];        // kk[B][T] -> later w
  __shared__ float bufC[Nc];        // tl chunk [32][128] -> later s[T][F]
  __shared__ float faL[Fc][Fc + 1]; // +1 pad: power-iter reads column-ish
  __shared__ float rs_ta[Tc];
  __shared__ float rs_fa[Fc];
  __shared__ float wqv[Fc], wkv[Fc];
  __shared__ float red[16];
  __shared__ float bcast;

  // ---- wq/wk = W0 @ tq, W0 @ tk ----
  if (tid < Fc) {
    const float* W0 = weight + h * (Fc * HDc);
    float aq = 0.f, ak = 0.f;
    for (int d = 0; d < HDc; ++d) {
      float w0 = W0[tid * HDc + d];
      aq += w0 * tqg[h * HDc + d];
      ak += w0 * tkg[h * HDc + d];
    }
    wqv[tid] = aq; wkv[tid] = ak;
  }
  // ---- fa scores: leaky_relu(U V^T) ----
  {
    const float* U = ffg + h * (2 * Fc * RKc);
    const float* V = U + Fc * RKc;
    int f1 = tid >> 5, f2 = tid & 31;
    float acc = 0.f;
    for (int r = 0; r < RKc; ++r) acc += U[f1 * RKc + r] * V[f2 * RKc + r];
    faL[f1][f2] = (acc >= 0.f) ? acc : ALPHA_LR * acc;
  }
  __syncthreads();

  // ---- fa softmax(axis=1) + threshold + rowsum ----
  {
    int f1 = tid >> 5, f2 = tid & 31;
    float val = faL[f1][f2];
    float m = val;
    for (int o = 16; o > 0; o >>= 1) m = fmaxf(m, __shfl_xor(m, o, 32));
    float e = expf(val - m);
    float se = e;
    for (int o = 16; o > 0; o >>= 1) se += __shfl_xor(se, o, 32);
    float p = e / se;
    p = (p > 0.01f && f1 != f2) ? p : 0.f;
    faL[f1][f2] = p;  // each thread only touched its own element
    float rs = p;
    for (int o = 16; o > 0; o >>= 1) rs += __shfl_xor(rs, o, 32);
    if (f2 == 0) rs_fa[f1] = rs;
    ws_fa[h * (Fc * Fc) + f1 * Fc + f2] = p;
  }

  // ---- q[b][t], kk[b][t] (q = x @ (W0 tq)) ----
  for (int p = tid; p < Bc * Tc; p += 1024) {
    const float4* xr4 = (const float4*)(x + (size_t)p * Fc);
    float aq = 0.f, ak = 0.f;
#pragma unroll
    for (int j = 0; j < Fc / 4; ++j) {
      float4 xv = xr4[j];
      aq += xv.x * wqv[4*j] + xv.y * wqv[4*j+1] + xv.z * wqv[4*j+2] + xv.w * wqv[4*j+3];
      ak += xv.x * wkv[4*j] + xv.y * wkv[4*j+1] + xv.z * wkv[4*j+2] + xv.w * wkv[4*j+3];
    }
    bufA[p] = aq; bufB[p] = ak;
  }
  __syncthreads();

  // ---- temporal attention, 4 chunks of 32 rows ----
  const int taBase = h * (Tc * Tc);
  for (int chunk = 0; chunk < 4; ++chunk) {
#pragma unroll
    for (int k = 0; k < 4; ++k) {
      int idx = tid + k * 1024;
      int r = idx >> 7, t2 = idx & 127;
      int t1 = chunk * 32 + r;
      float acc = 0.f;
      for (int bb = 0; bb < Bc; ++bb) {
        float sv = bufA[bb * Tc + t1] + bufB[bb * Tc + t2];
        acc += (sv >= 0.f) ? sv : ALPHA_LR * sv;
      }
      bufC[idx] = acc * (1.0f / 32.0f);  // mean over batch
    }
    __syncthreads();
    // softmax rows: wave wv handles rows 2wv, 2wv+1 of this chunk
#pragma unroll
    for (int rr2 = 0; rr2 < 2; ++rr2) {
      int rr = wv * 2 + rr2;
      int t1 = chunk * 32 + rr;
      float a0 = bufC[rr * 128 + lane];
      float a1 = bufC[rr * 128 + lane + 64];
      float m = fmaxf(a0, a1);
      for (int o = 32; o > 0; o >>= 1) m = fmaxf(m, __shfl_xor(m, o, 64));
      float e0 = expf(a0 - m), e1 = expf(a1 - m);
      float se = e0 + e1;
      for (int o = 32; o > 0; o >>= 1) se += __shfl_xor(se, o, 64);
      float p0 = e0 / se, p1 = e1 / se;
      p0 = (p0 > 0.01f && t1 != lane) ? p0 : 0.f;
      p1 = (p1 > 0.01f && t1 != (lane + 64)) ? p1 : 0.f;
      float rs = p0 + p1;
      for (int o = 32; o > 0; o >>= 1) rs += __shfl_xor(rs, o, 64);
      if (lane == 0) rs_ta[t1] = rs;
      ws_ta[taBase + t1 * Tc + lane] = p0;
      ws_ta[taBase + t1 * Tc + lane + 64] = p1;
      ws_taT[taBase + lane * Tc + t1] = p0;
      ws_taT[taBase + (lane + 64) * Tc + t1] = p1;
    }
    __syncthreads();
  }

  // ---- s[t][f] = (rowsum_ta[t] + rowsum_fa[f] + 1 + 1e-10)^-1/2 ----
#pragma unroll
  for (int k = 0; k < 4; ++k) {
    int idx = tid + k * 1024;
    int t = idx >> 5, f = idx & 31;
    float d = rs_ta[t] + rs_fa[f] + 1.0f + 1e-10f;
    float sv = 1.0f / sqrtf(d);
    bufC[idx] = sv;
    ws_s[h * Nc + idx] = sv;
  }

  // ---- v0 = jax.random.normal(fold_in(key(42), h), (n,1)) ----
  {
    uint32_t fk0 = 0u, fk1 = (uint32_t)h;     // threefry_seed(h) = [0, h]
    threefry2x32(0u, 42u, fk0, fk1);          // fold_in: encrypt with key [0,42]
    for (int i = tid; i < Nc / 2; i += 1024) {
      uint32_t c0 = (uint32_t)i, c1 = (uint32_t)(i + Nc / 2);
      threefry2x32(fk0, fk1, c0, c1);         // bits for iota split halves
      bufA[i]           = jax_normal_from_bits(c0);
      bufA[i + Nc / 2]  = jax_normal_from_bits(c1);
    }
  }
  __syncthreads();

  // ---- power iteration: 3x (v = Lv; v /= (||v||+1e-10)), then sn = |v^T L v| ----
  const float* taH = ws_ta + taBase;
  for (int it = 0; it < 4; ++it) {
    // w = s .* v
#pragma unroll
    for (int k = 0; k < 4; ++k) {
      int idx = tid + k * 1024;
      bufB[idx] = bufC[idx] * bufA[idx];
    }
    __syncthreads();
    float part = 0.f;
#pragma unroll
    for (int k = 0; k < 4; ++k) {
      int idx = tid + k * 1024;
      int t = idx >> 5, f = idx & 31;
      float acc = bufB[idx];                   // identity part of adj
      const float* tarow = taH + t * Tc;
#pragma unroll 8
      for (int t2 = 0; t2 < Tc; ++t2) acc += tarow[t2] * bufB[t2 * Fc + f];
#pragma unroll
      for (int f2 = 0; f2 < Fc; ++f2) acc += faL[f][f2] * bufB[t * Fc + f2];
      float nv = bufA[idx] - bufC[idx] * acc;  // (Lv)[idx]
      if (it < 3) { bufA[idx] = nv; part += nv * nv; }
      else        { part += bufA[idx] * nv; }  // Rayleigh v^T L v
    }
    for (int o = 32; o > 0; o >>= 1) part += __shfl_down(part, o, 64);
    if (lane == 0) red[wv] = part;
    __syncthreads();
    if (tid < 16) {
      float r = red[tid];
      for (int o = 8; o > 0; o >>= 1) r += __shfl_down(r, o, 16);
      if (tid == 0) bcast = r;
    }
    __syncthreads();
    if (it < 3) {
      float dv = sqrtf(bcast) + 1e-10f;
#pragma unroll
      for (int k = 0; k < 4; ++k) {
        int idx = tid + k * 1024;
        bufA[idx] = bufA[idx] / dv;
      }
      __syncthreads();
    } else if (tid == 0) {
      ws_sn[h] = fmaxf(fabsf(bcast), 1.0f);
    }
  }
}

// ---------------------------------------------------------------------------
// Stage B: one block per (batch, head). out = X@W0 + (x@L_scaled)@W1 + bias
// x@L_scaled = (2/sn)*(X - s.*(ta^T Z + Z fa + Z)) - X,  Z = s.*X
// ---------------------------------------------------------------------------
__global__ __launch_bounds__(256)
void stageB_kernel(const float* __restrict__ x, const float* __restrict__ weight,
                   const float* __restrict__ bias, const float* __restrict__ ws_taT,
                   const float* __restrict__ ws_fa, const float* __restrict__ ws_s,
                   const float* __restrict__ ws_sn, float* __restrict__ out) {
  const int b = blockIdx.x, h = blockIdx.y;
  const int tid = (int)threadIdx.x;
  __shared__ float X[Nc];
  __shared__ float Z[Nc];
  __shared__ float faL[Fc][Fc];
  __shared__ float W0s[Fc * HDc];
  __shared__ float W1s[Fc * HDc];

  const float* xb = x + (size_t)b * Nc;
  for (int i = tid; i < Nc / 4; i += 256)
    ((float4*)X)[i] = ((const float4*)xb)[i];
  for (int i = tid; i < Fc * Fc; i += 256)
    (&faL[0][0])[i] = ws_fa[h * Fc * Fc + i];
  for (int i = tid; i < Fc * HDc; i += 256) {
    W0s[i] = weight[h * (Fc * HDc) + i];
    W1s[i] = weight[(Hc + h) * (Fc * HDc) + i];
  }
  __syncthreads();
  const float* sH = ws_s + h * Nc;
  for (int i = tid; i < Nc; i += 256) Z[i] = sH[i] * X[i];
  __syncthreads();

  const float c = 2.0f / ws_sn[h];
  const float* taTH = ws_taT + h * (Tc * Tc);
  const int f = tid & 31, tg = tid >> 5;
  float G[16];
#pragma unroll
  for (int k = 0; k < 16; ++k) {
    int t = tg * 16 + k;
    float acc = Z[t * Fc + f];
    const float* trow = taTH + t * Tc;
#pragma unroll 8
    for (int t2 = 0; t2 < Tc; ++t2) acc += trow[t2] * Z[t2 * Fc + f];
#pragma unroll
    for (int f2 = 0; f2 < Fc; ++f2) acc += Z[t * Fc + f2] * faL[f2][f];
    G[k] = X[t * Fc + f] * (c - 1.0f) - c * sH[t * Fc + f] * acc;
  }
  __syncthreads();
#pragma unroll
  for (int k = 0; k < 16; ++k) Z[(tg * 16 + k) * Fc + f] = G[k];
  __syncthreads();

  const int hd = tid & 15, tq2 = tid >> 4;
  float* outb = out + (size_t)b * Tc * (Hc * HDc) + h * HDc;
#pragma unroll
  for (int k2 = 0; k2 < 8; ++k2) {
    int t = tq2 + 16 * k2;
    float acc = bias[h * HDc + hd];
#pragma unroll
    for (int f2 = 0; f2 < Fc; ++f2)
      acc += X[t * Fc + f2] * W0s[f2 * HDc + hd] + Z[t * Fc + f2] * W1s[f2 * HDc + hd];
    outb[t * (Hc * HDc) + hd] = acc;
  }
}

extern "C" void kernel_launch(void* const* d_in, const int* in_sizes, int n_in,
                              void* d_out, int out_size, void* d_ws, size_t ws_size,
                              hipStream_t stream) {
  const float* x      = (const float*)d_in[0];
  const float* weight = (const float*)d_in[1];
  const float* bias   = (const float*)d_in[2];
  const float* tqg    = (const float*)d_in[3];
  const float* tkg    = (const float*)d_in[4];
  const float* ffg    = (const float*)d_in[5];
  float* out = (float*)d_out;

  float* ws = (float*)d_ws;
  float* ws_ta  = ws;                 // 4 * 16384
  float* ws_taT = ws + 65536;         // 4 * 16384
  float* ws_fa  = ws + 131072;        // 4 * 1024
  float* ws_s   = ws + 135168;        // 4 * 4096
  float* ws_sn  = ws + 151552;        // 4

  stageA_kernel<<<dim3(Hc), dim3(1024), 0, stream>>>(
      x, weight, tqg, tkg, ffg, ws_ta, ws_taT, ws_fa, ws_s, ws_sn);
  stageB_kernel<<<dim3(Bc, Hc), dim3(256), 0, stream>>>(
      x, weight, bias, ws_taT, ws_fa, ws_s, ws_sn, out);
}

// Round 2
// 99.292 us; speedup vs baseline: 1.8979x; 1.8979x over previous
//
#include <hip/hip_runtime.h>
#include <cstdint>

static constexpr int Bc = 32, Tc = 128, Fc = 32, Hc = 4, HDc = 16, RKc = 16;
static constexpr int Nc = Tc * Fc;  // 4096
static constexpr int TAS = 132;     // taL row stride (pad)
static constexpr int WTS = 132;     // wT row stride
static constexpr int WRS = 36;      // row-major [*][32] stride (pad)

__device__ __forceinline__ uint32_t rotl32(uint32_t v, int r) {
  return (v << r) | (v >> (32 - r));
}

// Threefry-2x32, 20 rounds (JAX's PRNG cipher).
__device__ __forceinline__ void threefry2x32(uint32_t k0, uint32_t k1,
                                             uint32_t& x0, uint32_t& x1) {
  uint32_t k2 = k0 ^ k1 ^ 0x1BD11BDAu;
  x0 += k0; x1 += k1;
#define TF_R(r) { x0 += x1; x1 = rotl32(x1, (r)); x1 ^= x0; }
  TF_R(13) TF_R(15) TF_R(26) TF_R(6)
  x0 += k1; x1 += k2 + 1u;
  TF_R(17) TF_R(29) TF_R(16) TF_R(24)
  x0 += k2; x1 += k0 + 2u;
  TF_R(13) TF_R(15) TF_R(26) TF_R(6)
  x0 += k0; x1 += k1 + 3u;
  TF_R(17) TF_R(29) TF_R(16) TF_R(24)
  x0 += k1; x1 += k2 + 4u;
  TF_R(13) TF_R(15) TF_R(26) TF_R(6)
  x0 += k2; x1 += k0 + 5u;
#undef TF_R
}

// XLA ErfInv32 (Giles 2012) — matches lax.erf_inv on f32.
__device__ __forceinline__ float erfinv_f32(float x) {
  float w = -logf((1.0f - x) * (1.0f + x));
  float p;
  if (w < 5.0f) {
    w -= 2.5f;
    p = 2.81022636e-08f;
    p = fmaf(p, w, 3.43273939e-07f);
    p = fmaf(p, w, -3.5233877e-06f);
    p = fmaf(p, w, -4.39150654e-06f);
    p = fmaf(p, w, 0.00021858087f);
    p = fmaf(p, w, -0.00125372503f);
    p = fmaf(p, w, -0.00417768164f);
    p = fmaf(p, w, 0.246640727f);
    p = fmaf(p, w, 1.50140941f);
  } else {
    w = sqrtf(w) - 3.0f;
    p = -0.000200214257f;
    p = fmaf(p, w, 0.000100950558f);
    p = fmaf(p, w, 0.00134934322f);
    p = fmaf(p, w, -0.00367342844f);
    p = fmaf(p, w, 0.00573950773f);
    p = fmaf(p, w, -0.0076224613f);
    p = fmaf(p, w, 0.00943887047f);
    p = fmaf(p, w, 1.00167406f);
    p = fmaf(p, w, 2.83297682f);
  }
  return p * x;
}

__device__ __forceinline__ float jax_normal_from_bits(uint32_t bits) {
  const float lo = -0.99999994f;
  float f = __uint_as_float((bits >> 9) | 0x3f800000u) - 1.0f;
  float u = fmaxf(lo, f * 2.0f + lo);
  return 1.41421354f * erfinv_f32(u);
}

// ---------------------------------------------------------------------------
// Stage A: one block per head, 512 threads.
// ---------------------------------------------------------------------------
__global__ __launch_bounds__(512)
void stageA_kernel(const float* __restrict__ x, const float* __restrict__ weight,
                   const float* __restrict__ tqg, const float* __restrict__ tkg,
                   const float* __restrict__ ffg,
                   float* __restrict__ ws_taT, float* __restrict__ ws_fa,
                   float* __restrict__ ws_s, float* __restrict__ ws_sn) {
  const int h = blockIdx.x;
  const int tid = (int)threadIdx.x;
  const int lane = tid & 63;
  const int wv = tid >> 6;   // 0..7

  __shared__ __align__(16) float taL[Tc * TAS];   // 67.6 KB: scores -> ta
  __shared__ __align__(16) float uA[Fc * WTS];    // q[b][t] (stride 128) -> wT[f][t]
  __shared__ __align__(16) float uB[Tc * WRS];    // kk[b][t] (stride 128) -> w[t][f]
  __shared__ __align__(16) float faS[Fc * WRS];
  __shared__ float wqv[Fc], wkv[Fc];
  __shared__ float rs_ta[Tc];
  __shared__ float rs_fa[Fc];
  __shared__ float red[8];
  __shared__ float bcast;

  float* qS = uA;  // [32][128] (4096 <= 4224)
  float* kS = uB;  // [32][128] (4096 <= 4608)

  // ---- P0: wq/wk = W0 @ tq, W0 @ tk ----
  if (tid < Fc) {
    const float* W0 = weight + h * (Fc * HDc);
    float aq = 0.f, ak = 0.f;
    for (int d = 0; d < HDc; ++d) {
      float w0 = W0[tid * HDc + d];
      aq += w0 * tqg[h * HDc + d];
      ak += w0 * tkg[h * HDc + d];
    }
    wqv[tid] = aq; wkv[tid] = ak;
  }
  // ---- P0b: fa = threshold(softmax(leaky_relu(U V^T))) ----
  for (int j2 = tid; j2 < Fc * Fc; j2 += 512) {
    const float* U = ffg + h * (2 * Fc * RKc);
    const float* V = U + Fc * RKc;
    int f1 = j2 >> 5, f2 = j2 & 31;
    float acc = 0.f;
    for (int r = 0; r < RKc; ++r) acc += U[f1 * RKc + r] * V[f2 * RKc + r];
    float val = fmaxf(acc, 0.2f * acc);
    float m = val;
    for (int o = 16; o > 0; o >>= 1) m = fmaxf(m, __shfl_xor(m, o, 32));
    float e = expf(val - m), se = e;
    for (int o = 16; o > 0; o >>= 1) se += __shfl_xor(se, o, 32);
    float p = e / se;
    p = (p > 0.01f && f1 != f2) ? p : 0.f;
    faS[f1 * WRS + f2] = p;
    float rs = p;
    for (int o = 16; o > 0; o >>= 1) rs += __shfl_xor(rs, o, 32);
    if (f2 == 0) rs_fa[f1] = rs;
    ws_fa[h * (Fc * Fc) + j2] = p;
  }
  __syncthreads();

  // ---- P1: q[b][t], kk[b][t] ----
  for (int p = tid; p < Bc * Tc; p += 512) {
    const float4* xr4 = (const float4*)(x + (size_t)p * Fc);
    float aq = 0.f, ak = 0.f;
#pragma unroll
    for (int j2 = 0; j2 < Fc / 4; ++j2) {
      float4 xv = xr4[j2];
      aq += xv.x * wqv[4*j2] + xv.y * wqv[4*j2+1] + xv.z * wqv[4*j2+2] + xv.w * wqv[4*j2+3];
      ak += xv.x * wkv[4*j2] + xv.y * wkv[4*j2+1] + xv.z * wkv[4*j2+2] + xv.w * wkv[4*j2+3];
    }
    qS[p] = aq; kS[p] = ak;
  }
  __syncthreads();

  // ---- P2: scores (mean over batch of leaky_relu(q+k)) -> taL, 4x4 tiles ----
  for (int tile = tid; tile < 1024; tile += 512) {
    const int t1_0 = (tile >> 5) * 4, t2_0 = (tile & 31) * 4;
    float acc[4][4] = {};
    for (int b = 0; b < Bc; ++b) {
      float4 q4 = *(const float4*)&qS[b * Tc + t1_0];
      float4 k4 = *(const float4*)&kS[b * Tc + t2_0];
      float qa[4] = {q4.x, q4.y, q4.z, q4.w};
      float ka[4] = {k4.x, k4.y, k4.z, k4.w};
#pragma unroll
      for (int i = 0; i < 4; ++i)
#pragma unroll
        for (int j2 = 0; j2 < 4; ++j2) {
          float sv = qa[i] + ka[j2];
          acc[i][j2] += fmaxf(sv, 0.2f * sv);
        }
    }
#pragma unroll
    for (int i = 0; i < 4; ++i) {
      float4 st = make_float4(acc[i][0] * (1.0f/32.0f), acc[i][1] * (1.0f/32.0f),
                              acc[i][2] * (1.0f/32.0f), acc[i][3] * (1.0f/32.0f));
      *(float4*)&taL[(t1_0 + i) * TAS + t2_0] = st;
    }
  }
  __syncthreads();

  // ---- P3: row softmax + threshold + rowsum (in-place on taL) ----
  for (int r = wv; r < Tc; r += 8) {
    float a0 = taL[r * TAS + lane];
    float a1 = taL[r * TAS + 64 + lane];
    float m = fmaxf(a0, a1);
    for (int o = 32; o > 0; o >>= 1) m = fmaxf(m, __shfl_xor(m, o, 64));
    float e0 = expf(a0 - m), e1 = expf(a1 - m);
    float se = e0 + e1;
    for (int o = 32; o > 0; o >>= 1) se += __shfl_xor(se, o, 64);
    float p0 = e0 / se, p1 = e1 / se;
    p0 = (p0 > 0.01f && r != lane) ? p0 : 0.f;
    p1 = (p1 > 0.01f && r != (lane + 64)) ? p1 : 0.f;
    taL[r * TAS + lane] = p0;
    taL[r * TAS + 64 + lane] = p1;
    float rs = p0 + p1;
    for (int o = 32; o > 0; o >>= 1) rs += __shfl_xor(rs, o, 64);
    if (lane == 0) rs_ta[r] = rs;
  }
  __syncthreads();

  // ---- P4: ws_taT (taT[a][b] = ta[b][a]) + ws_s ----
  {
    float* taTg = ws_taT + h * (Tc * Tc);
    for (int j2 = tid; j2 < Tc * Tc; j2 += 512) {
      int a = j2 >> 7, b2 = j2 & 127;
      taTg[j2] = taL[b2 * TAS + a];
    }
    for (int j2 = tid; j2 < Nc; j2 += 512) {
      int t = j2 >> 5, f = j2 & 31;
      ws_s[h * Nc + j2] = 1.0f / sqrtf(rs_ta[t] + rs_fa[f] + 1.0f + 1e-10f);
    }
  }

  // ---- P5: v0 (threefry), s tile, initial w (tid<256) ----
  float v_reg[4][4], s_reg[4][4];   // [j(f)][i(t)]
  const int fb = tid & 7, tb8 = (tid >> 3) & 7, wq2 = tid >> 6;
  const int tbase = wq2 * 32 + tb8;
  if (tid < 256) {
    uint32_t fk0 = 0u, fk1 = (uint32_t)h;
    threefry2x32(0u, 42u, fk0, fk1);
#pragma unroll
    for (int j2 = 0; j2 < 4; ++j2)
#pragma unroll
      for (int i = 0; i < 4; ++i) {
        int t = tbase + 8 * i, f = fb + 8 * j2;
        int l = t * Fc + f;
        int pr = l & 2047;
        uint32_t c0 = (uint32_t)pr, c1 = (uint32_t)(pr + 2048);
        threefry2x32(fk0, fk1, c0, c1);
        v_reg[j2][i] = jax_normal_from_bits(l < 2048 ? c0 : c1);
        s_reg[j2][i] = 1.0f / sqrtf(rs_ta[t] + rs_fa[f] + 1.0f + 1e-10f);
      }
#pragma unroll
    for (int j2 = 0; j2 < 4; ++j2)
#pragma unroll
      for (int i = 0; i < 4; ++i) {
        int t = tbase + 8 * i, f = fb + 8 * j2;
        float wval = s_reg[j2][i] * v_reg[j2][i];
        uA[f * WTS + t] = wval;   // wT[f][t]
        uB[t * WRS + f] = wval;   // w[t][f]
      }
  }
  __syncthreads();

  // ---- P6: power iteration (3 steps) + Rayleigh ----
  float nv[4][4];
  for (int it = 0; it < 4; ++it) {
    float partv = 0.f;
    if (tid < 256) {
      float acc[4][4] = {};   // [j(f)][i(t)]
      // M1[t][f] = sum_k ta[t][k] * wT[f][k]
      for (int k4 = 0; k4 < 32; ++k4) {
        float4 ta4[4], wt4[4];
#pragma unroll
        for (int i = 0; i < 4; ++i)
          ta4[i] = *(const float4*)&taL[(tbase + 8*i) * TAS + k4 * 4];
#pragma unroll
        for (int j2 = 0; j2 < 4; ++j2)
          wt4[j2] = *(const float4*)&uA[(fb + 8*j2) * WTS + k4 * 4];
#pragma unroll
        for (int j2 = 0; j2 < 4; ++j2)
#pragma unroll
          for (int i = 0; i < 4; ++i)
            acc[j2][i] += ta4[i].x * wt4[j2].x + ta4[i].y * wt4[j2].y +
                          ta4[i].z * wt4[j2].z + ta4[i].w * wt4[j2].w;
      }
      // M2[t][f] = sum_f2 fa[f][f2] * w[t][f2]
      for (int c4 = 0; c4 < 8; ++c4) {
        float4 fa4[4], wr4[4];
#pragma unroll
        for (int j2 = 0; j2 < 4; ++j2)
          fa4[j2] = *(const float4*)&faS[(fb + 8*j2) * WRS + c4 * 4];
#pragma unroll
        for (int i = 0; i < 4; ++i)
          wr4[i] = *(const float4*)&uB[(tbase + 8*i) * WRS + c4 * 4];
#pragma unroll
        for (int j2 = 0; j2 < 4; ++j2)
#pragma unroll
          for (int i = 0; i < 4; ++i)
            acc[j2][i] += fa4[j2].x * wr4[i].x + fa4[j2].y * wr4[i].y +
                          fa4[j2].z * wr4[i].z + fa4[j2].w * wr4[i].w;
      }
      // identity + Lv
#pragma unroll
      for (int j2 = 0; j2 < 4; ++j2)
#pragma unroll
        for (int i = 0; i < 4; ++i) {
          float a = acc[j2][i] + s_reg[j2][i] * v_reg[j2][i];   // + w (identity)
          float nvv = v_reg[j2][i] - s_reg[j2][i] * a;
          nv[j2][i] = nvv;
          partv += (it < 3) ? nvv * nvv : v_reg[j2][i] * nvv;
        }
    }
    // block reduce (waves 0..3 hold data)
    float pr2 = partv;
    for (int o = 32; o > 0; o >>= 1) pr2 += __shfl_down(pr2, o, 64);
    if (lane == 0) red[wv] = pr2;
    __syncthreads();
    if (tid == 0) bcast = red[0] + red[1] + red[2] + red[3];
    __syncthreads();
    if (it < 3) {
      if (tid < 256) {
        float inv = 1.0f / (sqrtf(bcast) + 1e-10f);
#pragma unroll
        for (int j2 = 0; j2 < 4; ++j2)
#pragma unroll
          for (int i = 0; i < 4; ++i) {
            float vnew = nv[j2][i] * inv;
            v_reg[j2][i] = vnew;
            float wval = s_reg[j2][i] * vnew;
            uA[(fb + 8*j2) * WTS + (tbase + 8*i)] = wval;
            uB[(tbase + 8*i) * WRS + (fb + 8*j2)] = wval;
          }
      }
      __syncthreads();
    } else if (tid == 0) {
      ws_sn[h] = fmaxf(fabsf(bcast), 1.0f);
    }
  }
}

// ---------------------------------------------------------------------------
// Stage B: one block per (batch, head), 256 threads.
// out = X@W0 + G@W1 + bias,  G = (c-1)X - c*s.*(taT@Z + Z@fa + Z),  c = 2/sn
// ---------------------------------------------------------------------------
__global__ __launch_bounds__(256)
void stageB_kernel(const float* __restrict__ x, const float* __restrict__ weight,
                   const float* __restrict__ bias, const float* __restrict__ ws_taT,
                   const float* __restrict__ ws_fa, const float* __restrict__ ws_s,
                   const float* __restrict__ ws_sn, float* __restrict__ out) {
  const int b = blockIdx.x, h = blockIdx.y;
  const int tid = (int)threadIdx.x;
  __shared__ __align__(16) float taTs[Tc * TAS];  // 67.6 KB
  __shared__ __align__(16) float Xs[Tc * WRS];
  __shared__ __align__(16) float Zs[Tc * WRS];
  __shared__ __align__(16) float Gs[Tc * WRS];
  __shared__ __align__(16) float faS[Fc * WRS];
  __shared__ __align__(16) float W0T[HDc * WRS];
  __shared__ __align__(16) float W1T[HDc * WRS];

  const float* taTg = ws_taT + h * (Tc * Tc);
  for (int j2 = tid; j2 < Tc * Tc / 4; j2 += 256) {
    int row = j2 >> 5, c4 = j2 & 31;
    *(float4*)&taTs[row * TAS + c4 * 4] = *(const float4*)&taTg[row * Tc + c4 * 4];
  }
  const float* xb = x + (size_t)b * Nc;
  const float* sH = ws_s + h * Nc;
  for (int j2 = tid; j2 < Nc / 4; j2 += 256) {
    int row = j2 >> 3, c4 = j2 & 7;
    float4 xv = *(const float4*)&xb[row * Fc + c4 * 4];
    float4 sv = *(const float4*)&sH[row * Fc + c4 * 4];
    *(float4*)&Xs[row * WRS + c4 * 4] = xv;
    float4 zv = make_float4(xv.x * sv.x, xv.y * sv.y, xv.z * sv.z, xv.w * sv.w);
    *(float4*)&Zs[row * WRS + c4 * 4] = zv;
  }
  for (int j2 = tid; j2 < Fc * Fc; j2 += 256) {
    faS[(j2 >> 5) * WRS + (j2 & 31)] = ws_fa[h * (Fc * Fc) + j2];
  }
  for (int j2 = tid; j2 < Fc * HDc; j2 += 256) {
    int f = j2 >> 4, hd = j2 & 15;
    W0T[hd * WRS + f] = weight[h * (Fc * HDc) + j2];
    W1T[hd * WRS + f] = weight[(Hc + h) * (Fc * HDc) + j2];
  }
  __syncthreads();

  const float csn = 2.0f / ws_sn[h];
  // ---- G: 4t x 4f tiles; t = tb + 32*i ----
  {
    const int f0 = (tid & 7) * 4, tb = tid >> 3;
    float4 acc4[4] = {};
    // G1[t][f] = sum_k taT[t][k] Z[k][f]
    for (int k4 = 0; k4 < 32; ++k4) {
      float4 ta4[4], z4[4];
#pragma unroll
      for (int i = 0; i < 4; ++i)
        ta4[i] = *(const float4*)&taTs[(tb + 32*i) * TAS + k4 * 4];
#pragma unroll
      for (int c = 0; c < 4; ++c)
        z4[c] = *(const float4*)&Zs[(k4 * 4 + c) * WRS + f0];
#pragma unroll
      for (int i = 0; i < 4; ++i) {
        acc4[i].x += ta4[i].x * z4[0].x + ta4[i].y * z4[1].x + ta4[i].z * z4[2].x + ta4[i].w * z4[3].x;
        acc4[i].y += ta4[i].x * z4[0].y + ta4[i].y * z4[1].y + ta4[i].z * z4[2].y + ta4[i].w * z4[3].y;
        acc4[i].z += ta4[i].x * z4[0].z + ta4[i].y * z4[1].z + ta4[i].z * z4[2].z + ta4[i].w * z4[3].z;
        acc4[i].w += ta4[i].x * z4[0].w + ta4[i].y * z4[1].w + ta4[i].z * z4[2].w + ta4[i].w * z4[3].w;
      }
    }
    // G2[t][f] = sum_f2 Z[t][f2] fa[f2][f]
    for (int c4 = 0; c4 < 8; ++c4) {
      float4 zr4[4], fa4[4];
#pragma unroll
      for (int i = 0; i < 4; ++i)
        zr4[i] = *(const float4*)&Zs[(tb + 32*i) * WRS + c4 * 4];
#pragma unroll
      for (int c = 0; c < 4; ++c)
        fa4[c] = *(const float4*)&faS[(c4 * 4 + c) * WRS + f0];
#pragma unroll
      for (int i = 0; i < 4; ++i) {
        acc4[i].x += zr4[i].x * fa4[0].x + zr4[i].y * fa4[1].x + zr4[i].z * fa4[2].x + zr4[i].w * fa4[3].x;
        acc4[i].y += zr4[i].x * fa4[0].y + zr4[i].y * fa4[1].y + zr4[i].z * fa4[2].y + zr4[i].w * fa4[3].y;
        acc4[i].z += zr4[i].x * fa4[0].z + zr4[i].y * fa4[1].z + zr4[i].z * fa4[2].z + zr4[i].w * fa4[3].z;
        acc4[i].w += zr4[i].x * fa4[0].w + zr4[i].y * fa4[1].w + zr4[i].z * fa4[2].w + zr4[i].w * fa4[3].w;
      }
    }
    // combine: G = (c-1)X - c * s .* (M + Z)
#pragma unroll
    for (int i = 0; i < 4; ++i) {
      int t = tb + 32 * i;
      float4 xv = *(const float4*)&Xs[t * WRS + f0];
      float4 zv = *(const float4*)&Zs[t * WRS + f0];
      float4 sv = *(const float4*)&sH[t * Fc + f0];
      float4 g;
      g.x = (csn - 1.0f) * xv.x - csn * sv.x * (acc4[i].x + zv.x);
      g.y = (csn - 1.0f) * xv.y - csn * sv.y * (acc4[i].y + zv.y);
      g.z = (csn - 1.0f) * xv.z - csn * sv.z * (acc4[i].z + zv.z);
      g.w = (csn - 1.0f) * xv.w - csn * sv.w * (acc4[i].w + zv.w);
      *(float4*)&Gs[t * WRS + f0] = g;
    }
  }
  __syncthreads();

  // ---- out GEMM: 4t x 2hd tiles ----
  {
    const int hd0 = (tid & 7) * 2, tb = tid >> 3;
    float acc[4][2] = {};
    for (int c4 = 0; c4 < 8; ++c4) {
      float4 w0a = *(const float4*)&W0T[hd0 * WRS + c4 * 4];
      float4 w0b = *(const float4*)&W0T[(hd0 + 1) * WRS + c4 * 4];
      float4 w1a = *(const float4*)&W1T[hd0 * WRS + c4 * 4];
      float4 w1b = *(const float4*)&W1T[(hd0 + 1) * WRS + c4 * 4];
#pragma unroll
      for (int i = 0; i < 4; ++i) {
        int t = tb + 32 * i;
        float4 xv = *(const float4*)&Xs[t * WRS + c4 * 4];
        float4 gv = *(const float4*)&Gs[t * WRS + c4 * 4];
        acc[i][0] += xv.x * w0a.x + xv.y * w0a.y + xv.z * w0a.z + xv.w * w0a.w +
                     gv.x * w1a.x + gv.y * w1a.y + gv.z * w1a.z + gv.w * w1a.w;
        acc[i][1] += xv.x * w0b.x + xv.y * w0b.y + xv.z * w0b.z + xv.w * w0b.w +
                     gv.x * w1b.x + gv.y * w1b.y + gv.z * w1b.z + gv.w * w1b.w;
      }
    }
    float b0 = bias[h * HDc + hd0], b1 = bias[h * HDc + hd0 + 1];
    float* outb = out + (size_t)b * Tc * (Hc * HDc) + h * HDc;
#pragma unroll
    for (int i = 0; i < 4; ++i) {
      int t = tb + 32 * i;
      float2 o2 = make_float2(acc[i][0] + b0, acc[i][1] + b1);
      *(float2*)&outb[t * (Hc * HDc) + hd0] = o2;
    }
  }
}

extern "C" void kernel_launch(void* const* d_in, const int* in_sizes, int n_in,
                              void* d_out, int out_size, void* d_ws, size_t ws_size,
                              hipStream_t stream) {
  const float* x      = (const float*)d_in[0];
  const float* weight = (const float*)d_in[1];
  const float* bias   = (const float*)d_in[2];
  const float* tqg    = (const float*)d_in[3];
  const float* tkg    = (const float*)d_in[4];
  const float* ffg    = (const float*)d_in[5];
  float* out = (float*)d_out;

  float* ws = (float*)d_ws;
  float* ws_taT = ws;                 // 4 * 16384 = 65536
  float* ws_fa  = ws + 65536;         // 4 * 1024  = 4096
  float* ws_s   = ws + 69632;         // 4 * 4096  = 16384
  float* ws_sn  = ws + 86016;         // 4

  stageA_kernel<<<dim3(Hc), dim3(512), 0, stream>>>(
      x, weight, tqg, tkg, ffg, ws_taT, ws_fa, ws_s, ws_sn);
  stageB_kernel<<<dim3(Bc, Hc), dim3(256), 0, stream>>>(
      x, weight, bias, ws_taT, ws_fa, ws_s, ws_sn, out);
}

// Round 3
// 62.419 us; speedup vs baseline: 3.0192x; 1.5907x over previous
//
#include <hip/hip_runtime.h>
#include <cstdint>

static constexpr int Bc = 32, Tc = 128, Fc = 32, Hc = 4, HDc = 16, RKc = 16;
static constexpr int Nc = Tc * Fc;  // 4096
static constexpr int TAS = 132;     // ta LDS row stride
static constexpr int WLS = 36;      // w LDS row stride
static constexpr int XS  = 36;      // [*][32] row stride

__device__ __forceinline__ uint32_t rotl32(uint32_t v, int r) {
  return (v << r) | (v >> (32 - r));
}

// Threefry-2x32, 20 rounds (JAX's PRNG cipher).
__device__ __forceinline__ void threefry2x32(uint32_t k0, uint32_t k1,
                                             uint32_t& x0, uint32_t& x1) {
  uint32_t k2 = k0 ^ k1 ^ 0x1BD11BDAu;
  x0 += k0; x1 += k1;
#define TF_R(r) { x0 += x1; x1 = rotl32(x1, (r)); x1 ^= x0; }
  TF_R(13) TF_R(15) TF_R(26) TF_R(6)
  x0 += k1; x1 += k2 + 1u;
  TF_R(17) TF_R(29) TF_R(16) TF_R(24)
  x0 += k2; x1 += k0 + 2u;
  TF_R(13) TF_R(15) TF_R(26) TF_R(6)
  x0 += k0; x1 += k1 + 3u;
  TF_R(17) TF_R(29) TF_R(16) TF_R(24)
  x0 += k1; x1 += k2 + 4u;
  TF_R(13) TF_R(15) TF_R(26) TF_R(6)
  x0 += k2; x1 += k0 + 5u;
#undef TF_R
}

// XLA ErfInv32 (Giles 2012) — matches lax.erf_inv on f32.
__device__ __forceinline__ float erfinv_f32(float x) {
  float w = -logf((1.0f - x) * (1.0f + x));
  float p;
  if (w < 5.0f) {
    w -= 2.5f;
    p = 2.81022636e-08f;
    p = fmaf(p, w, 3.43273939e-07f);
    p = fmaf(p, w, -3.5233877e-06f);
    p = fmaf(p, w, -4.39150654e-06f);
    p = fmaf(p, w, 0.00021858087f);
    p = fmaf(p, w, -0.00125372503f);
    p = fmaf(p, w, -0.00417768164f);
    p = fmaf(p, w, 0.246640727f);
    p = fmaf(p, w, 1.50140941f);
  } else {
    w = sqrtf(w) - 3.0f;
    p = -0.000200214257f;
    p = fmaf(p, w, 0.000100950558f);
    p = fmaf(p, w, 0.00134934322f);
    p = fmaf(p, w, -0.00367342844f);
    p = fmaf(p, w, 0.00573950773f);
    p = fmaf(p, w, -0.0076224613f);
    p = fmaf(p, w, 0.00943887047f);
    p = fmaf(p, w, 1.00167406f);
    p = fmaf(p, w, 2.83297682f);
  }
  return p * x;
}

__device__ __forceinline__ float jax_normal_from_bits(uint32_t bits) {
  const float lo = -0.99999994f;
  float f = __uint_as_float((bits >> 9) | 0x3f800000u) - 1.0f;
  float u = fmaxf(lo, f * 2.0f + lo);
  return 1.41421354f * erfinv_f32(u);
}

// ---------------------------------------------------------------------------
// K1: scores. grid (h, t1chunk=8), 256 threads. tl[h][t1][t2] -> ws_tlta.
// ---------------------------------------------------------------------------
__global__ __launch_bounds__(256)
void score_kernel(const float* __restrict__ x, const float* __restrict__ weight,
                  const float* __restrict__ tqg, const float* __restrict__ tkg,
                  float* __restrict__ ws_tlta) {
  const int h = blockIdx.x, t1c = blockIdx.y;
  const int tid = (int)threadIdx.x;
  __shared__ float kS[Bc][Tc];
  __shared__ float qS[Bc][16];
  __shared__ float wqv[Fc], wkv[Fc];

  if (tid < Fc) {
    const float* W0 = weight + h * (Fc * HDc);
    float aq = 0.f, ak = 0.f;
    for (int d = 0; d < HDc; ++d) {
      float w0 = W0[tid * HDc + d];
      aq += w0 * tqg[h * HDc + d];
      ak += w0 * tkg[h * HDc + d];
    }
    wqv[tid] = aq; wkv[tid] = ak;
  }
  __syncthreads();

  for (int i = tid; i < Bc * Tc; i += 256) {
    const float4* xr = (const float4*)(x + (size_t)i * Fc);
    float ak = 0.f;
#pragma unroll
    for (int j = 0; j < 8; ++j) {
      float4 v = xr[j];
      ak += v.x * wkv[4*j] + v.y * wkv[4*j+1] + v.z * wkv[4*j+2] + v.w * wkv[4*j+3];
    }
    kS[i >> 7][i & 127] = ak;
  }
  for (int i = tid; i < Bc * 16; i += 256) {
    int b = i >> 4, tt = i & 15;
    const float4* xr = (const float4*)(x + ((size_t)b * Tc + 16 * t1c + tt) * Fc);
    float aq = 0.f;
#pragma unroll
    for (int j = 0; j < 8; ++j) {
      float4 v = xr[j];
      aq += v.x * wqv[4*j] + v.y * wqv[4*j+1] + v.z * wqv[4*j+2] + v.w * wqv[4*j+3];
    }
    qS[b][tt] = aq;
  }
  __syncthreads();

  const int t1l = tid >> 4, t2g = tid & 15;
  float acc[8] = {};
  for (int b = 0; b < Bc; ++b) {
    float q = qS[b][t1l];
    float4 k0 = *(const float4*)&kS[b][8 * t2g];
    float4 k1 = *(const float4*)&kS[b][8 * t2g + 4];
    float kv[8] = {k0.x, k0.y, k0.z, k0.w, k1.x, k1.y, k1.z, k1.w};
#pragma unroll
    for (int j = 0; j < 8; ++j) {
      float s = q + kv[j];
      acc[j] += fmaxf(s, 0.2f * s);
    }
  }
  float* o = ws_tlta + ((size_t)h * Tc + 16 * t1c + t1l) * Tc + 8 * t2g;
  *(float4*)o       = make_float4(acc[0]*(1.f/32.f), acc[1]*(1.f/32.f), acc[2]*(1.f/32.f), acc[3]*(1.f/32.f));
  *(float4*)(o + 4) = make_float4(acc[4]*(1.f/32.f), acc[5]*(1.f/32.f), acc[6]*(1.f/32.f), acc[7]*(1.f/32.f));
}

// ---------------------------------------------------------------------------
// K2: per-head finalize. grid (4), 512 threads.
// softmax(ta)+threshold, fa, s, flag, taT (only if any ta!=0), power iter, sn.
// ---------------------------------------------------------------------------
__global__ __launch_bounds__(512)
void head_kernel(const float* __restrict__ ffg, float* __restrict__ ws_tlta,
                 float* __restrict__ ws_fa, float* __restrict__ ws_s,
                 float* __restrict__ ws_sn, float* __restrict__ ws_flag) {
  const int h = blockIdx.x;
  const int tid = (int)threadIdx.x;
  const int lane = tid & 63, wv = tid >> 6;

  __shared__ __align__(16) float taL[Tc * TAS];   // 67.6 KB
  __shared__ __align__(16) float wL[Tc * WLS];    // 18.4 KB
  __shared__ __align__(16) float faTS[Fc * XS];   // faT[f2][f1]
  __shared__ float rs_ta[Tc], rs_fa[Fc], red[8];
  __shared__ float bcastS;
  __shared__ int flagS;

  float* tlg = ws_tlta + (size_t)h * Tc * Tc;

  // stage scores -> taL
  for (int i = tid; i < Tc * Tc / 4; i += 512) {
    int row = i >> 5, c4 = i & 31;
    *(float4*)&taL[row * TAS + 4 * c4] = *(const float4*)&tlg[row * Tc + 4 * c4];
  }
  // fa (+faT in LDS, fa row-major to global)
  for (int j2 = tid; j2 < Fc * Fc; j2 += 512) {
    const float* U = ffg + h * (2 * Fc * RKc);
    const float* V = U + Fc * RKc;
    int f1 = j2 >> 5, f2 = j2 & 31;
    float acc = 0.f;
    for (int r = 0; r < RKc; ++r) acc += U[f1 * RKc + r] * V[f2 * RKc + r];
    float val = fmaxf(acc, 0.2f * acc);
    float m = val;
    for (int o = 16; o > 0; o >>= 1) m = fmaxf(m, __shfl_xor(m, o, 32));
    float e = expf(val - m), se = e;
    for (int o = 16; o > 0; o >>= 1) se += __shfl_xor(se, o, 32);
    float p = e / se;
    p = (p > 0.01f && f1 != f2) ? p : 0.f;
    faTS[f2 * XS + f1] = p;
    ws_fa[h * Fc * Fc + j2] = p;
    float rs = p;
    for (int o = 16; o > 0; o >>= 1) rs += __shfl_xor(rs, o, 32);
    if (f2 == 0) rs_fa[f1] = rs;
  }
  __syncthreads();

  // softmax rows of ta (in place) + threshold + rowsums
  for (int r = wv; r < Tc; r += 8) {
    float a0 = taL[r * TAS + lane], a1 = taL[r * TAS + 64 + lane];
    float m = fmaxf(a0, a1);
    for (int o = 32; o > 0; o >>= 1) m = fmaxf(m, __shfl_xor(m, o, 64));
    float e0 = expf(a0 - m), e1 = expf(a1 - m);
    float se = e0 + e1;
    for (int o = 32; o > 0; o >>= 1) se += __shfl_xor(se, o, 64);
    float p0 = e0 / se, p1 = e1 / se;
    p0 = (p0 > 0.01f && r != lane) ? p0 : 0.f;
    p1 = (p1 > 0.01f && r != (lane + 64)) ? p1 : 0.f;
    taL[r * TAS + lane] = p0;
    taL[r * TAS + 64 + lane] = p1;
    float rs = p0 + p1;
    for (int o = 32; o > 0; o >>= 1) rs += __shfl_xor(rs, o, 64);
    if (lane == 0) rs_ta[r] = rs;
  }
  __syncthreads();

  // exact any-nonzero flag (rowsums of nonneg matrix)
  if (tid < 64) {
    int nz = (rs_ta[tid] > 0.f) || (rs_ta[tid + 64] > 0.f);
    unsigned long long bal = __ballot(nz);
    if (tid == 0) { flagS = (bal != 0ull) ? 1 : 0; ws_flag[h] = (bal != 0ull) ? 1.f : 0.f; }
  }
  __syncthreads();

  if (flagS) {  // uniform branch: write taT (over the dead tl region)
    for (int i = tid; i < Tc * Tc; i += 512) {
      int a = i >> 7, b2 = i & 127;
      tlg[i] = taL[b2 * TAS + a];
    }
  }
  // s to global
  for (int i = tid; i < Nc; i += 512) {
    int t = i >> 5, f = i & 31;
    ws_s[h * Nc + i] = 1.0f / sqrtf(rs_ta[t] + rs_fa[f] + 1.0f + 1e-10f);
  }

  // v0 + power iteration. thread = (t = tid>>2, fb = tid&3), f-range 8*fb..+8
  const int t = tid >> 2, fb = tid & 3;
  float v_reg[8], s_reg[8], nv[8];
  {
    uint32_t fk0 = 0u, fk1 = (uint32_t)h;
    threefry2x32(0u, 42u, fk0, fk1);
#pragma unroll
    for (int j = 0; j < 8; ++j) {
      int f = 8 * fb + j;
      int l = t * Fc + f;
      int pr = l & 2047;
      uint32_t c0 = (uint32_t)pr, c1 = (uint32_t)(pr + 2048);
      threefry2x32(fk0, fk1, c0, c1);
      v_reg[j] = jax_normal_from_bits(l < 2048 ? c0 : c1);
      s_reg[j] = 1.0f / sqrtf(rs_ta[t] + rs_fa[f] + 1.0f + 1e-10f);
    }
    float w[8];
#pragma unroll
    for (int j = 0; j < 8; ++j) w[j] = s_reg[j] * v_reg[j];
    *(float4*)&wL[t * WLS + 8 * fb]     = make_float4(w[0], w[1], w[2], w[3]);
    *(float4*)&wL[t * WLS + 8 * fb + 4] = make_float4(w[4], w[5], w[6], w[7]);
  }
  __syncthreads();

  for (int it = 0; it < 4; ++it) {
    float acc[8] = {};
    if (flagS) {  // M1[t][f] = sum_k ta[t][k] w[k][f]  (skipped when ta==0)
      for (int k4 = 0; k4 < 32; ++k4) {
        float4 ta4 = *(const float4*)&taL[t * TAS + 4 * k4];
        float tav[4] = {ta4.x, ta4.y, ta4.z, ta4.w};
#pragma unroll
        for (int c = 0; c < 4; ++c) {
          const float* wr = &wL[(4 * k4 + c) * WLS + 8 * fb];
          float4 w0 = *(const float4*)wr, w1 = *(const float4*)(wr + 4);
          acc[0] += tav[c] * w0.x; acc[1] += tav[c] * w0.y;
          acc[2] += tav[c] * w0.z; acc[3] += tav[c] * w0.w;
          acc[4] += tav[c] * w1.x; acc[5] += tav[c] * w1.y;
          acc[6] += tav[c] * w1.z; acc[7] += tav[c] * w1.w;
        }
      }
    }
    // M2[t][f] = sum_f2 w[t][f2] * faT[f2][f]
    for (int f24 = 0; f24 < 8; ++f24) {
      float4 w4 = *(const float4*)&wL[t * WLS + 4 * f24];
      float wv4[4] = {w4.x, w4.y, w4.z, w4.w};
#pragma unroll
      for (int c = 0; c < 4; ++c) {
        const float* fr = &faTS[(4 * f24 + c) * XS + 8 * fb];
        float4 fa0 = *(const float4*)fr, fa1 = *(const float4*)(fr + 4);
        acc[0] += wv4[c] * fa0.x; acc[1] += wv4[c] * fa0.y;
        acc[2] += wv4[c] * fa0.z; acc[3] += wv4[c] * fa0.w;
        acc[4] += wv4[c] * fa1.x; acc[5] += wv4[c] * fa1.y;
        acc[6] += wv4[c] * fa1.z; acc[7] += wv4[c] * fa1.w;
      }
    }
    float partv = 0.f;
#pragma unroll
    for (int j = 0; j < 8; ++j) {
      float a = acc[j] + s_reg[j] * v_reg[j];   // + identity term
      float nvv = v_reg[j] - s_reg[j] * a;      // (Lv)
      nv[j] = nvv;
      partv += (it < 3) ? nvv * nvv : v_reg[j] * nvv;
    }
    for (int o = 32; o > 0; o >>= 1) partv += __shfl_down(partv, o, 64);
    if (lane == 0) red[wv] = partv;
    __syncthreads();
    if (tid == 0) {
      float s2 = 0.f;
      for (int i2 = 0; i2 < 8; ++i2) s2 += red[i2];
      bcastS = s2;
    }
    __syncthreads();
    if (it < 3) {
      float inv = 1.0f / (sqrtf(bcastS) + 1e-10f);
      float w[8];
#pragma unroll
      for (int j = 0; j < 8; ++j) {
        v_reg[j] = nv[j] * inv;
        w[j] = s_reg[j] * v_reg[j];
      }
      *(float4*)&wL[t * WLS + 8 * fb]     = make_float4(w[0], w[1], w[2], w[3]);
      *(float4*)&wL[t * WLS + 8 * fb + 4] = make_float4(w[4], w[5], w[6], w[7]);
      __syncthreads();
    } else if (tid == 0) {
      ws_sn[h] = fmaxf(fabsf(bcastS), 1.0f);
    }
  }
}

// ---------------------------------------------------------------------------
// K3: conv. grid (b, h) = 128 blocks, 256 threads.
// G = (c-1)X - c*s.*(taT@Z + Z@fa + Z),  out = X@W0 + G@W1 + bias
// ---------------------------------------------------------------------------
__global__ __launch_bounds__(256)
void conv_kernel(const float* __restrict__ x, const float* __restrict__ weight,
                 const float* __restrict__ bias, const float* __restrict__ ws_tlta,
                 const float* __restrict__ ws_fa, const float* __restrict__ ws_s,
                 const float* __restrict__ ws_sn, const float* __restrict__ ws_flag,
                 float* __restrict__ out) {
  const int b = blockIdx.x, h = blockIdx.y;
  const int tid = (int)threadIdx.x;
  __shared__ __align__(16) float taTs[Tc * TAS];  // 67.6 KB (used only if flag)
  __shared__ __align__(16) float Xs[Tc * XS];
  __shared__ __align__(16) float Zs[Tc * XS];
  __shared__ __align__(16) float Gs[Tc * XS];
  __shared__ __align__(16) float Ss[Tc * XS];
  __shared__ __align__(16) float faS[Fc * XS];    // fa[f2][f] rows
  __shared__ __align__(16) float W0s[Fc * HDc];
  __shared__ __align__(16) float W1s[Fc * HDc];

  const float* xb = x + (size_t)b * Nc;
  const float* sH = ws_s + h * Nc;
  for (int i = tid; i < Nc / 4; i += 256) {
    int row = i >> 3, c4 = i & 7;
    float4 xv = *(const float4*)&xb[row * Fc + 4 * c4];
    float4 sv = *(const float4*)&sH[row * Fc + 4 * c4];
    *(float4*)&Xs[row * XS + 4 * c4] = xv;
    *(float4*)&Ss[row * XS + 4 * c4] = sv;
    *(float4*)&Zs[row * XS + 4 * c4] =
        make_float4(xv.x * sv.x, xv.y * sv.y, xv.z * sv.z, xv.w * sv.w);
  }
  for (int i = tid; i < Fc * Fc; i += 256)
    faS[(i >> 5) * XS + (i & 31)] = ws_fa[h * Fc * Fc + i];
  for (int i = tid; i < Fc * HDc; i += 256) {
    W0s[i] = weight[h * (Fc * HDc) + i];
    W1s[i] = weight[(Hc + h) * (Fc * HDc) + i];
  }
  const int flag = (ws_flag[h] != 0.f);
  const float csn = 2.0f / ws_sn[h];
  __syncthreads();

  // ---- G phase: thread = (tt = tid&63, sel = tid>>6), rows {tt, tt+64}, f0=8*sel
  {
    const int tt = tid & 63, f0 = 8 * (tid >> 6);
    float acc[2][8] = {};
    if (flag) {
      const float* taTg = ws_tlta + (size_t)h * Tc * Tc;
      for (int i = tid; i < Tc * Tc / 4; i += 256) {
        int row = i >> 5, c4 = i & 31;
        *(float4*)&taTs[row * TAS + 4 * c4] = *(const float4*)&taTg[row * Tc + 4 * c4];
      }
      __syncthreads();
      for (int k4 = 0; k4 < 32; ++k4) {
        float4 a0 = *(const float4*)&taTs[tt * TAS + 4 * k4];
        float4 a1 = *(const float4*)&taTs[(tt + 64) * TAS + 4 * k4];
        float av0[4] = {a0.x, a0.y, a0.z, a0.w};
        float av1[4] = {a1.x, a1.y, a1.z, a1.w};
#pragma unroll
        for (int c = 0; c < 4; ++c) {
          const float* zr = &Zs[(4 * k4 + c) * XS + f0];
          float4 z0 = *(const float4*)zr, z1 = *(const float4*)(zr + 4);
          acc[0][0] += av0[c] * z0.x; acc[0][1] += av0[c] * z0.y;
          acc[0][2] += av0[c] * z0.z; acc[0][3] += av0[c] * z0.w;
          acc[0][4] += av0[c] * z1.x; acc[0][5] += av0[c] * z1.y;
          acc[0][6] += av0[c] * z1.z; acc[0][7] += av0[c] * z1.w;
          acc[1][0] += av1[c] * z0.x; acc[1][1] += av1[c] * z0.y;
          acc[1][2] += av1[c] * z0.z; acc[1][3] += av1[c] * z0.w;
          acc[1][4] += av1[c] * z1.x; acc[1][5] += av1[c] * z1.y;
          acc[1][6] += av1[c] * z1.z; acc[1][7] += av1[c] * z1.w;
        }
      }
    }
    // Z @ fa : sum_f2 Z[t][f2] * fa[f2][f]
    for (int f24 = 0; f24 < 8; ++f24) {
      float4 z40 = *(const float4*)&Zs[tt * XS + 4 * f24];
      float4 z41 = *(const float4*)&Zs[(tt + 64) * XS + 4 * f24];
      float zv0[4] = {z40.x, z40.y, z40.z, z40.w};
      float zv1[4] = {z41.x, z41.y, z41.z, z41.w};
#pragma unroll
      for (int c = 0; c < 4; ++c) {
        const float* fr = &faS[(4 * f24 + c) * XS + f0];
        float4 fa0 = *(const float4*)fr, fa1 = *(const float4*)(fr + 4);
        acc[0][0] += zv0[c] * fa0.x; acc[0][1] += zv0[c] * fa0.y;
        acc[0][2] += zv0[c] * fa0.z; acc[0][3] += zv0[c] * fa0.w;
        acc[0][4] += zv0[c] * fa1.x; acc[0][5] += zv0[c] * fa1.y;
        acc[0][6] += zv0[c] * fa1.z; acc[0][7] += zv0[c] * fa1.w;
        acc[1][0] += zv1[c] * fa0.x; acc[1][1] += zv1[c] * fa0.y;
        acc[1][2] += zv1[c] * fa0.z; acc[1][3] += zv1[c] * fa0.w;
        acc[1][4] += zv1[c] * fa1.x; acc[1][5] += zv1[c] * fa1.y;
        acc[1][6] += zv1[c] * fa1.z; acc[1][7] += zv1[c] * fa1.w;
      }
    }
    const float cm1 = csn - 1.0f;
#pragma unroll
    for (int r = 0; r < 2; ++r) {
      int t = tt + 64 * r;
      float4 xv0 = *(const float4*)&Xs[t * XS + f0], xv1 = *(const float4*)&Xs[t * XS + f0 + 4];
      float4 zv0 = *(const float4*)&Zs[t * XS + f0], zv1 = *(const float4*)&Zs[t * XS + f0 + 4];
      float4 sv0 = *(const float4*)&Ss[t * XS + f0], sv1 = *(const float4*)&Ss[t * XS + f0 + 4];
      float4 g0, g1;
      g0.x = cm1 * xv0.x - csn * sv0.x * (acc[r][0] + zv0.x);
      g0.y = cm1 * xv0.y - csn * sv0.y * (acc[r][1] + zv0.y);
      g0.z = cm1 * xv0.z - csn * sv0.z * (acc[r][2] + zv0.z);
      g0.w = cm1 * xv0.w - csn * sv0.w * (acc[r][3] + zv0.w);
      g1.x = cm1 * xv1.x - csn * sv1.x * (acc[r][4] + zv1.x);
      g1.y = cm1 * xv1.y - csn * sv1.y * (acc[r][5] + zv1.y);
      g1.z = cm1 * xv1.z - csn * sv1.z * (acc[r][6] + zv1.z);
      g1.w = cm1 * xv1.w - csn * sv1.w * (acc[r][7] + zv1.w);
      *(float4*)&Gs[t * XS + f0]     = g0;
      *(float4*)&Gs[t * XS + f0 + 4] = g1;
    }
  }
  __syncthreads();

  // ---- out GEMM: thread = (tt = tid&63, hb = tid>>6), rows {tt, tt+64}, hd 4*hb..+4
  {
    const int tt = tid & 63, hb = tid >> 6;
    float acc2[2][4] = {};
    for (int f4g = 0; f4g < 8; ++f4g) {
      float4 x0 = *(const float4*)&Xs[tt * XS + 4 * f4g];
      float4 g0 = *(const float4*)&Gs[tt * XS + 4 * f4g];
      float4 x1 = *(const float4*)&Xs[(tt + 64) * XS + 4 * f4g];
      float4 g1 = *(const float4*)&Gs[(tt + 64) * XS + 4 * f4g];
      float xa0[4] = {x0.x, x0.y, x0.z, x0.w}, ga0[4] = {g0.x, g0.y, g0.z, g0.w};
      float xa1[4] = {x1.x, x1.y, x1.z, x1.w}, ga1[4] = {g1.x, g1.y, g1.z, g1.w};
#pragma unroll
      for (int c = 0; c < 4; ++c) {
        int f = 4 * f4g + c;
        float4 w0 = *(const float4*)&W0s[f * HDc + 4 * hb];
        float4 w1 = *(const float4*)&W1s[f * HDc + 4 * hb];
        acc2[0][0] += xa0[c] * w0.x + ga0[c] * w1.x;
        acc2[0][1] += xa0[c] * w0.y + ga0[c] * w1.y;
        acc2[0][2] += xa0[c] * w0.z + ga0[c] * w1.z;
        acc2[0][3] += xa0[c] * w0.w + ga0[c] * w1.w;
        acc2[1][0] += xa1[c] * w0.x + ga1[c] * w1.x;
        acc2[1][1] += xa1[c] * w0.y + ga1[c] * w1.y;
        acc2[1][2] += xa1[c] * w0.z + ga1[c] * w1.z;
        acc2[1][3] += xa1[c] * w0.w + ga1[c] * w1.w;
      }
    }
    float4 bv = *(const float4*)&bias[h * HDc + 4 * hb];
#pragma unroll
    for (int r = 0; r < 2; ++r) {
      int t = tt + 64 * r;
      float4 o4 = make_float4(acc2[r][0] + bv.x, acc2[r][1] + bv.y,
                              acc2[r][2] + bv.z, acc2[r][3] + bv.w);
      *(float4*)&out[((size_t)b * Tc + t) * (Hc * HDc) + h * HDc + 4 * hb] = o4;
    }
  }
}

extern "C" void kernel_launch(void* const* d_in, const int* in_sizes, int n_in,
                              void* d_out, int out_size, void* d_ws, size_t ws_size,
                              hipStream_t stream) {
  const float* x      = (const float*)d_in[0];
  const float* weight = (const float*)d_in[1];
  const float* bias   = (const float*)d_in[2];
  const float* tqg    = (const float*)d_in[3];
  const float* tkg    = (const float*)d_in[4];
  const float* ffg    = (const float*)d_in[5];
  float* out = (float*)d_out;

  float* ws = (float*)d_ws;
  float* ws_tlta = ws;            // 4*16384 = 65536 (scores, then taT in place)
  float* ws_fa   = ws + 65536;    // 4096
  float* ws_s    = ws + 69632;    // 16384
  float* ws_sn   = ws + 86016;    // 4
  float* ws_flag = ws + 86020;    // 4

  score_kernel<<<dim3(Hc, 8), dim3(256), 0, stream>>>(x, weight, tqg, tkg, ws_tlta);
  head_kernel<<<dim3(Hc), dim3(512), 0, stream>>>(ffg, ws_tlta, ws_fa, ws_s, ws_sn, ws_flag);
  conv_kernel<<<dim3(Bc, Hc), dim3(256), 0, stream>>>(x, weight, bias, ws_tlta, ws_fa,
                                                      ws_s, ws_sn, ws_flag, out);
}

// Round 5
// 52.126 us; speedup vs baseline: 3.6153x; 1.1975x over previous
//
#include <hip/hip_runtime.h>
#include <cstdint>

static constexpr int Bc = 32, Tc = 128, Fc = 32, Hc = 4, HDc = 16, RKc = 16;
static constexpr int Nc = Tc * Fc;  // 4096
static constexpr int WS36 = 36;     // row-major [*][32] padded stride
static constexpr int TS = 132;      // transposed [32][128] padded stride

__device__ __forceinline__ uint32_t rotl32(uint32_t v, int r) {
  return (v << r) | (v >> (32 - r));
}

__device__ __forceinline__ void threefry2x32(uint32_t k0, uint32_t k1,
                                             uint32_t& x0, uint32_t& x1) {
  uint32_t k2 = k0 ^ k1 ^ 0x1BD11BDAu;
  x0 += k0; x1 += k1;
#define TF_R(r) { x0 += x1; x1 = rotl32(x1, (r)); x1 ^= x0; }
  TF_R(13) TF_R(15) TF_R(26) TF_R(6)
  x0 += k1; x1 += k2 + 1u;
  TF_R(17) TF_R(29) TF_R(16) TF_R(24)
  x0 += k2; x1 += k0 + 2u;
  TF_R(13) TF_R(15) TF_R(26) TF_R(6)
  x0 += k0; x1 += k1 + 3u;
  TF_R(17) TF_R(29) TF_R(16) TF_R(24)
  x0 += k1; x1 += k2 + 4u;
  TF_R(13) TF_R(15) TF_R(26) TF_R(6)
  x0 += k2; x1 += k0 + 5u;
#undef TF_R
}

__device__ __forceinline__ float erfinv_f32(float x) {
  float w = -logf((1.0f - x) * (1.0f + x));
  float p;
  if (w < 5.0f) {
    w -= 2.5f;
    p = 2.81022636e-08f;
    p = fmaf(p, w, 3.43273939e-07f);
    p = fmaf(p, w, -3.5233877e-06f);
    p = fmaf(p, w, -4.39150654e-06f);
    p = fmaf(p, w, 0.00021858087f);
    p = fmaf(p, w, -0.00125372503f);
    p = fmaf(p, w, -0.00417768164f);
    p = fmaf(p, w, 0.246640727f);
    p = fmaf(p, w, 1.50140941f);
  } else {
    w = sqrtf(w) - 3.0f;
    p = -0.000200214257f;
    p = fmaf(p, w, 0.000100950558f);
    p = fmaf(p, w, 0.00134934322f);
    p = fmaf(p, w, -0.00367342844f);
    p = fmaf(p, w, 0.00573950773f);
    p = fmaf(p, w, -0.0076224613f);
    p = fmaf(p, w, 0.00943887047f);
    p = fmaf(p, w, 1.00167406f);
    p = fmaf(p, w, 2.83297682f);
  }
  return p * x;
}

__device__ __forceinline__ float jax_normal_from_bits(uint32_t bits) {
  const float lo = -0.99999994f;
  float f = __uint_as_float((bits >> 9) | 0x3f800000u) - 1.0f;
  float u = fmaxf(lo, f * 2.0f + lo);
  return 1.41421354f * erfinv_f32(u);
}

// ---------------------------------------------------------------------------
// K1: scores + row softmax + threshold + per-row CSR. grid (h, t1chunk=8), 256 thr.
// CSR row segment base is fixed at row*Tc (no atomics, deterministic).
// ---------------------------------------------------------------------------
__global__ __launch_bounds__(256)
void score_kernel(const float* __restrict__ x, const float* __restrict__ weight,
                  const float* __restrict__ tqg, const float* __restrict__ tkg,
                  float* __restrict__ ws_ta, float* __restrict__ ws_rs,
                  int* __restrict__ ws_rowcnt, int* __restrict__ ws_cols,
                  float* __restrict__ ws_vals) {
  const int h = blockIdx.x, t1c = blockIdx.y;
  const int tid = (int)threadIdx.x;
  __shared__ float kS[Bc][Tc];
  __shared__ float qS[Bc][16];
  __shared__ float wqv[Fc], wkv[Fc];

  if (tid < Fc) {
    const float* W0 = weight + h * (Fc * HDc);
    float aq = 0.f, ak = 0.f;
    for (int d = 0; d < HDc; ++d) {
      float w0 = W0[tid * HDc + d];
      aq += w0 * tqg[h * HDc + d];
      ak += w0 * tkg[h * HDc + d];
    }
    wqv[tid] = aq; wkv[tid] = ak;
  }
  __syncthreads();

  for (int i = tid; i < Bc * Tc; i += 256) {
    const float4* xr = (const float4*)(x + (size_t)i * Fc);
    float ak = 0.f;
#pragma unroll
    for (int j = 0; j < 8; ++j) {
      float4 v = xr[j];
      ak += v.x * wkv[4*j] + v.y * wkv[4*j+1] + v.z * wkv[4*j+2] + v.w * wkv[4*j+3];
    }
    kS[i >> 7][i & 127] = ak;
  }
  for (int i = tid; i < Bc * 16; i += 256) {
    int b = i >> 4, tt = i & 15;
    const float4* xr = (const float4*)(x + ((size_t)b * Tc + 16 * t1c + tt) * Fc);
    float aq = 0.f;
#pragma unroll
    for (int j = 0; j < 8; ++j) {
      float4 v = xr[j];
      aq += v.x * wqv[4*j] + v.y * wqv[4*j+1] + v.z * wqv[4*j+2] + v.w * wqv[4*j+3];
    }
    qS[b][tt] = aq;
  }
  __syncthreads();

  const int t1l = tid >> 4, t2g = tid & 15, gl = tid & 15;
  const int gt1 = 16 * t1c + t1l;
  float acc[8] = {};
  for (int b = 0; b < Bc; ++b) {
    float q = qS[b][t1l];
    float4 k0 = *(const float4*)&kS[b][8 * t2g];
    float4 k1 = *(const float4*)&kS[b][8 * t2g + 4];
    float kv[8] = {k0.x, k0.y, k0.z, k0.w, k1.x, k1.y, k1.z, k1.w};
#pragma unroll
    for (int j = 0; j < 8; ++j) {
      float s = q + kv[j];
      acc[j] += fmaxf(s, 0.2f * s);
    }
  }
#pragma unroll
  for (int j = 0; j < 8; ++j) acc[j] *= (1.0f / 32.0f);

  // softmax over the row (16-lane group holds 128 values, 8/lane)
  float m = acc[0];
#pragma unroll
  for (int j = 1; j < 8; ++j) m = fmaxf(m, acc[j]);
  for (int o = 8; o > 0; o >>= 1) m = fmaxf(m, __shfl_xor(m, o, 16));
  float e[8], se = 0.f;
#pragma unroll
  for (int j = 0; j < 8; ++j) { e[j] = expf(acc[j] - m); se += e[j]; }
  for (int o = 8; o > 0; o >>= 1) se += __shfl_xor(se, o, 16);
  float p[8]; int keep[8]; int cnt = 0; float rs = 0.f;
#pragma unroll
  for (int j = 0; j < 8; ++j) {
    float pv = e[j] / se;
    int col = 8 * t2g + j;
    int k = (pv > 0.01f) && (col != gt1);
    p[j] = k ? pv : 0.f;
    keep[j] = k;
    cnt += k;
    rs += p[j];
  }
  for (int o = 8; o > 0; o >>= 1) rs += __shfl_xor(rs, o, 16);

  // dense thresholded row to global (row-major, coalesced)
  float* tar = ws_ta + (size_t)h * (Tc * Tc) + (size_t)gt1 * Tc + 8 * t2g;
  *(float4*)tar       = make_float4(p[0], p[1], p[2], p[3]);
  *(float4*)(tar + 4) = make_float4(p[4], p[5], p[6], p[7]);

  // per-row CSR segment at base gt1*Tc (ascending-col -> deterministic sums)
  int ci = cnt;
  for (int o = 1; o < 16; o <<= 1) {
    int u = __shfl_up(ci, o, 16);
    if (gl >= o) ci += u;
  }
  int excl = ci - cnt;
  int total = __shfl(ci, 15, 16);
  if (gl == 0) {
    ws_rowcnt[h * Tc + gt1] = total;
    ws_rs[h * Tc + gt1] = rs;
  }
  int off = gt1 * Tc + excl;
#pragma unroll
  for (int j = 0; j < 8; ++j) {
    if (keep[j]) {
      ws_cols[h * (Tc * Tc) + off] = 8 * t2g + j;
      ws_vals[h * (Tc * Tc) + off] = p[j];
      ++off;
    }
  }
}

// ---------------------------------------------------------------------------
// K2: per-head. fa, rs_fa, nz flag, PRNG v0, sparse power iteration, sn.
// grid(4), 512 threads.
// ---------------------------------------------------------------------------
__global__ __launch_bounds__(512)
void head_kernel(const float* __restrict__ ffg, const float* __restrict__ ws_rs,
                 float* __restrict__ ws_fa, float* __restrict__ ws_rsfa,
                 float* __restrict__ ws_sn, int* __restrict__ ws_nz,
                 const int* __restrict__ ws_rowcnt, const int* __restrict__ ws_cols,
                 const float* __restrict__ ws_vals) {
  const int h = blockIdx.x;
  const int tid = (int)threadIdx.x;
  const int lane = tid & 63, wv = tid >> 6;

  __shared__ __align__(16) float faTS[Fc * WS36];  // faT[f2][f1]
  __shared__ __align__(16) float wL[Tc * WS36];    // w[t][f]
  __shared__ __align__(16) float wTL[Fc * TS];     // wT[f][t]
  __shared__ float rsT[Tc], rsF[Fc], red[8];
  __shared__ float bcastS;
  __shared__ int rcS[Tc];

  // fa = threshold(softmax(leaky_relu(U V^T), axis=1))
  for (int j2 = tid; j2 < Fc * Fc; j2 += 512) {
    const float* U = ffg + h * (2 * Fc * RKc);
    const float* V = U + Fc * RKc;
    int f1 = j2 >> 5, f2 = j2 & 31;
    float acc = 0.f;
    for (int r = 0; r < RKc; ++r) acc += U[f1 * RKc + r] * V[f2 * RKc + r];
    float val = fmaxf(acc, 0.2f * acc);
    float m = val;
    for (int o = 16; o > 0; o >>= 1) m = fmaxf(m, __shfl_xor(m, o, 32));
    float e = expf(val - m), se = e;
    for (int o = 16; o > 0; o >>= 1) se += __shfl_xor(se, o, 32);
    float pv = e / se;
    pv = (pv > 0.01f && f1 != f2) ? pv : 0.f;
    faTS[f2 * WS36 + f1] = pv;
    ws_fa[h * (Fc * Fc) + j2] = pv;
    float rsum = pv;
    for (int o = 16; o > 0; o >>= 1) rsum += __shfl_xor(rsum, o, 32);
    if (f2 == 0) { rsF[f1] = rsum; ws_rsfa[h * Fc + f1] = rsum; }
  }
  if (tid < Tc) {
    rsT[tid] = ws_rs[h * Tc + tid];
    rcS[tid] = ws_rowcnt[h * Tc + tid];
  }
  __syncthreads();

  // nz flag for this head (single writer)
  if (tid < 64) {
    int nz = (rcS[tid] != 0) || (rcS[tid + 64] != 0);
    unsigned long long bal = __ballot(nz);
    if (tid == 0) ws_nz[h] = (bal != 0ull) ? 1 : 0;
  }

  // thread mapping: rows {tq, tq+64}, f = 4*fb .. +4
  const int tq = tid & 63, fb = tid >> 6, f0 = 4 * fb;
  float v_reg[2][4], s_reg[2][4], nv[2][4];
#pragma unroll
  for (int r = 0; r < 2; ++r) {
    float rrow = rsT[tq + 64 * r];
#pragma unroll
    for (int j = 0; j < 4; ++j)
      s_reg[r][j] = 1.0f / sqrtf(rrow + rsF[f0 + j] + 1.0f + 1e-10f);
  }
  {
    uint32_t fk0 = 0u, fk1 = (uint32_t)h;
    threefry2x32(0u, 42u, fk0, fk1);
#pragma unroll
    for (int j = 0; j < 4; ++j) {
      int l = tq * Fc + f0 + j;  // < 2048 always
      uint32_t c0 = (uint32_t)l, c1 = (uint32_t)(l + 2048);
      threefry2x32(fk0, fk1, c0, c1);
      v_reg[0][j] = jax_normal_from_bits(c0);   // element (tq, f)
      v_reg[1][j] = jax_normal_from_bits(c1);   // element (tq+64, f)
    }
  }
#pragma unroll
  for (int r = 0; r < 2; ++r) {
    int t = tq + 64 * r;
    float w[4];
#pragma unroll
    for (int j = 0; j < 4; ++j) w[j] = s_reg[r][j] * v_reg[r][j];
    *(float4*)&wL[t * WS36 + f0] = make_float4(w[0], w[1], w[2], w[3]);
#pragma unroll
    for (int j = 0; j < 4; ++j) wTL[(f0 + j) * TS + t] = w[j];
  }
  __syncthreads();

  const int csrBase = h * (Tc * Tc);
  for (int it = 0; it < 4; ++it) {
    float acc[2][4] = {};
    // M1 (sparse): row segment at base t*Tc, ascending col order
#pragma unroll
    for (int r = 0; r < 2; ++r) {
      int t = tq + 64 * r;
      int bse = csrBase + t * Tc, cnt = rcS[t];
      for (int e = 0; e < cnt; ++e) {
        int col = ws_cols[bse + e];
        float val = ws_vals[bse + e];
        float4 w4 = *(const float4*)&wL[col * WS36 + f0];
        acc[r][0] += val * w4.x; acc[r][1] += val * w4.y;
        acc[r][2] += val * w4.z; acc[r][3] += val * w4.w;
      }
    }
    // M2: fa @ w[t,:]  ->  sum_f2 fa[f][f2] * w[t][f2]
    for (int f2 = 0; f2 < Fc; ++f2) {
      float4 fav = *(const float4*)&faTS[f2 * WS36 + f0];  // broadcast (f0 uniform/wave)
      float w0 = wTL[f2 * TS + tq];
      float w1 = wTL[f2 * TS + tq + 64];
      acc[0][0] += w0 * fav.x; acc[0][1] += w0 * fav.y;
      acc[0][2] += w0 * fav.z; acc[0][3] += w0 * fav.w;
      acc[1][0] += w1 * fav.x; acc[1][1] += w1 * fav.y;
      acc[1][2] += w1 * fav.z; acc[1][3] += w1 * fav.w;
    }
    float partv = 0.f;
#pragma unroll
    for (int r = 0; r < 2; ++r)
#pragma unroll
      for (int j = 0; j < 4; ++j) {
        float a = acc[r][j] + s_reg[r][j] * v_reg[r][j];  // + identity part
        float nvv = v_reg[r][j] - s_reg[r][j] * a;        // (Lv)
        nv[r][j] = nvv;
        partv += (it < 3) ? nvv * nvv : v_reg[r][j] * nvv;
      }
    for (int o = 32; o > 0; o >>= 1) partv += __shfl_down(partv, o, 64);
    if (lane == 0) red[wv] = partv;
    __syncthreads();
    if (tid == 0) {
      float s2 = 0.f;
      for (int i2 = 0; i2 < 8; ++i2) s2 += red[i2];
      bcastS = s2;
    }
    __syncthreads();
    if (it < 3) {
      float inv = 1.0f / (sqrtf(bcastS) + 1e-10f);
#pragma unroll
      for (int r = 0; r < 2; ++r) {
        int t = tq + 64 * r;
        float w[4];
#pragma unroll
        for (int j = 0; j < 4; ++j) {
          v_reg[r][j] = nv[r][j] * inv;
          w[j] = s_reg[r][j] * v_reg[r][j];
        }
        *(float4*)&wL[t * WS36 + f0] = make_float4(w[0], w[1], w[2], w[3]);
#pragma unroll
        for (int j = 0; j < 4; ++j) wTL[(f0 + j) * TS + t] = w[j];
      }
      __syncthreads();
    } else if (tid == 0) {
      ws_sn[h] = fmaxf(fabsf(bcastS), 1.0f);
    }
  }
}

// ---------------------------------------------------------------------------
// K3: conv. grid (b, h) = 128 blocks, 256 threads. All LDS reads broadcast or
// lane-consecutive (conflict-free).
// ---------------------------------------------------------------------------
__global__ __launch_bounds__(256)
void conv_kernel(const float* __restrict__ x, const float* __restrict__ weight,
                 const float* __restrict__ bias, const float* __restrict__ ws_ta,
                 const float* __restrict__ ws_fa, const float* __restrict__ ws_rs,
                 const float* __restrict__ ws_rsfa, const float* __restrict__ ws_sn,
                 const int* __restrict__ ws_nz, float* __restrict__ out) {
  const int b = blockIdx.x, h = blockIdx.y;
  const int tid = (int)threadIdx.x;
  __shared__ __align__(16) float taS[Tc * Tc];    // 64 KB (staged only if nz)
  __shared__ __align__(16) float Zs[Tc * WS36];   // Z row-major (broadcast reads)
  __shared__ __align__(16) float ZT[Fc * TS];     // Z^T
  __shared__ __align__(16) float XT[Fc * TS];     // X^T
  __shared__ __align__(16) float GT[Fc * TS];     // G^T
  __shared__ __align__(16) float faS[Fc * WS36];  // fa row-major [f2][f]
  __shared__ __align__(16) float W0s[Fc * HDc];
  __shared__ __align__(16) float W1s[Fc * HDc];
  __shared__ float rsT[Tc], rsF[Fc];

  const int flag = (ws_nz[h] != 0);
  if (tid < Tc) rsT[tid] = ws_rs[h * Tc + tid];
  if (tid < Fc) rsF[tid] = ws_rsfa[h * Fc + tid];
  for (int i = tid; i < Fc * Fc; i += 256)
    faS[(i >> 5) * WS36 + (i & 31)] = ws_fa[h * (Fc * Fc) + i];
  for (int i = tid; i < Fc * HDc; i += 256) {
    W0s[i] = weight[h * (Fc * HDc) + i];
    W1s[i] = weight[(Hc + h) * (Fc * HDc) + i];
  }
  if (flag) {
    const float4* taG = (const float4*)(ws_ta + (size_t)h * (Tc * Tc));
    for (int i = tid; i < Tc * Tc / 4; i += 256) ((float4*)taS)[i] = taG[i];
  }
  __syncthreads();  // rsT/rsF ready for staging

  const float* xb = x + (size_t)b * Nc;
  for (int i = tid; i < Nc / 4; i += 256) {
    int row = i >> 3, c4 = i & 7;
    float4 xv = *(const float4*)&xb[row * Fc + 4 * c4];
    float rrow = rsT[row];
    float s0 = 1.0f / sqrtf(rrow + rsF[4 * c4 + 0] + 1.0f + 1e-10f);
    float s1 = 1.0f / sqrtf(rrow + rsF[4 * c4 + 1] + 1.0f + 1e-10f);
    float s2 = 1.0f / sqrtf(rrow + rsF[4 * c4 + 2] + 1.0f + 1e-10f);
    float s3 = 1.0f / sqrtf(rrow + rsF[4 * c4 + 3] + 1.0f + 1e-10f);
    float4 zv = make_float4(xv.x * s0, xv.y * s1, xv.z * s2, xv.w * s3);
    *(float4*)&Zs[row * WS36 + 4 * c4] = zv;
    XT[(4 * c4 + 0) * TS + row] = xv.x; ZT[(4 * c4 + 0) * TS + row] = zv.x;
    XT[(4 * c4 + 1) * TS + row] = xv.y; ZT[(4 * c4 + 1) * TS + row] = zv.y;
    XT[(4 * c4 + 2) * TS + row] = xv.z; ZT[(4 * c4 + 2) * TS + row] = zv.z;
    XT[(4 * c4 + 3) * TS + row] = xv.w; ZT[(4 * c4 + 3) * TS + row] = zv.w;
  }
  __syncthreads();

  const float csn = 2.0f / ws_sn[h];
  const float cm1 = csn - 1.0f;

  // ---- G phase: lanes = t (conflict-free), f0 = 8*(tid>>6) (wave-uniform)
  {
    const int tt = tid & 63, f0 = 8 * (tid >> 6);
    float acc[2][8] = {};
    if (flag) {
      for (int k = 0; k < Tc; ++k) {
        float ta0 = taS[k * Tc + tt];
        float ta1 = taS[k * Tc + tt + 64];
        float4 z0 = *(const float4*)&Zs[k * WS36 + f0];      // broadcast
        float4 z1 = *(const float4*)&Zs[k * WS36 + f0 + 4];  // broadcast
        acc[0][0] += ta0 * z0.x; acc[0][1] += ta0 * z0.y;
        acc[0][2] += ta0 * z0.z; acc[0][3] += ta0 * z0.w;
        acc[0][4] += ta0 * z1.x; acc[0][5] += ta0 * z1.y;
        acc[0][6] += ta0 * z1.z; acc[0][7] += ta0 * z1.w;
        acc[1][0] += ta1 * z0.x; acc[1][1] += ta1 * z0.y;
        acc[1][2] += ta1 * z0.z; acc[1][3] += ta1 * z0.w;
        acc[1][4] += ta1 * z1.x; acc[1][5] += ta1 * z1.y;
        acc[1][6] += ta1 * z1.z; acc[1][7] += ta1 * z1.w;
      }
    }
    // feature part: sum_f2 fa[f2][f] * Z[t][f2]
    for (int f2 = 0; f2 < Fc; ++f2) {
      float4 fa0 = *(const float4*)&faS[f2 * WS36 + f0];      // broadcast
      float4 fa1 = *(const float4*)&faS[f2 * WS36 + f0 + 4];  // broadcast
      float zt0 = ZT[f2 * TS + tt];
      float zt1 = ZT[f2 * TS + tt + 64];
      acc[0][0] += zt0 * fa0.x; acc[0][1] += zt0 * fa0.y;
      acc[0][2] += zt0 * fa0.z; acc[0][3] += zt0 * fa0.w;
      acc[0][4] += zt0 * fa1.x; acc[0][5] += zt0 * fa1.y;
      acc[0][6] += zt0 * fa1.z; acc[0][7] += zt0 * fa1.w;
      acc[1][0] += zt1 * fa0.x; acc[1][1] += zt1 * fa0.y;
      acc[1][2] += zt1 * fa0.z; acc[1][3] += zt1 * fa0.w;
      acc[1][4] += zt1 * fa1.x; acc[1][5] += zt1 * fa1.y;
      acc[1][6] += zt1 * fa1.z; acc[1][7] += zt1 * fa1.w;
    }
#pragma unroll
    for (int r = 0; r < 2; ++r) {
      int t = tt + 64 * r;
      float rrow = rsT[t];
#pragma unroll
      for (int j = 0; j < 8; ++j) {
        int f = f0 + j;
        float xv = XT[f * TS + t];
        float zv = ZT[f * TS + t];
        float sv = 1.0f / sqrtf(rrow + rsF[f] + 1.0f + 1e-10f);
        GT[f * TS + t] = cm1 * xv - csn * sv * (acc[r][j] + zv);
      }
    }
  }
  __syncthreads();

  // ---- out GEMM: lanes = t, hd-block = 4*(tid>>6) (wave-uniform)
  {
    const int tt = tid & 63, hb = tid >> 6;
    float acc2[2][4] = {};
    for (int f = 0; f < Fc; ++f) {
      float4 w0 = *(const float4*)&W0s[f * HDc + 4 * hb];  // broadcast
      float4 w1 = *(const float4*)&W1s[f * HDc + 4 * hb];  // broadcast
      float x0 = XT[f * TS + tt], x1 = XT[f * TS + tt + 64];
      float g0 = GT[f * TS + tt], g1 = GT[f * TS + tt + 64];
      acc2[0][0] += x0 * w0.x + g0 * w1.x;
      acc2[0][1] += x0 * w0.y + g0 * w1.y;
      acc2[0][2] += x0 * w0.z + g0 * w1.z;
      acc2[0][3] += x0 * w0.w + g0 * w1.w;
      acc2[1][0] += x1 * w0.x + g1 * w1.x;
      acc2[1][1] += x1 * w0.y + g1 * w1.y;
      acc2[1][2] += x1 * w0.z + g1 * w1.z;
      acc2[1][3] += x1 * w0.w + g1 * w1.w;
    }
    float4 bv = *(const float4*)&bias[h * HDc + 4 * hb];
#pragma unroll
    for (int r = 0; r < 2; ++r) {
      int t = tt + 64 * r;
      float4 o4 = make_float4(acc2[r][0] + bv.x, acc2[r][1] + bv.y,
                              acc2[r][2] + bv.z, acc2[r][3] + bv.w);
      *(float4*)&out[((size_t)b * Tc + t) * (Hc * HDc) + h * HDc + 4 * hb] = o4;
    }
  }
}

extern "C" void kernel_launch(void* const* d_in, const int* in_sizes, int n_in,
                              void* d_out, int out_size, void* d_ws, size_t ws_size,
                              hipStream_t stream) {
  const float* x      = (const float*)d_in[0];
  const float* weight = (const float*)d_in[1];
  const float* bias   = (const float*)d_in[2];
  const float* tqg    = (const float*)d_in[3];
  const float* tkg    = (const float*)d_in[4];
  const float* ffg    = (const float*)d_in[5];
  float* out = (float*)d_out;

  float* ws = (float*)d_ws;
  float* ws_ta     = ws;                    // 4*16384 = 65536
  float* ws_rs     = ws + 65536;            // 512
  float* ws_fa     = ws + 66048;            // 4096
  float* ws_rsfa   = ws + 70144;            // 128
  float* ws_sn     = ws + 70272;            // 4
  int*   ws_nz     = (int*)(ws + 70276);    // 4
  int*   ws_rowcnt = (int*)(ws + 70280);    // 512
  int*   ws_cols   = (int*)(ws + 70792);    // 65536
  float* ws_vals   = ws + 136328;           // 65536

  score_kernel<<<dim3(Hc, 8), dim3(256), 0, stream>>>(
      x, weight, tqg, tkg, ws_ta, ws_rs, ws_rowcnt, ws_cols, ws_vals);
  head_kernel<<<dim3(Hc), dim3(512), 0, stream>>>(
      ffg, ws_rs, ws_fa, ws_rsfa, ws_sn, ws_nz, ws_rowcnt, ws_cols, ws_vals);
  conv_kernel<<<dim3(Bc, Hc), dim3(256), 0, stream>>>(
      x, weight, bias, ws_ta, ws_fa, ws_rs, ws_rsfa, ws_sn, ws_nz, out);
}